// Round 5
// baseline (141.394 us; speedup 1.0000x reference)
//
#include <hip/hip_runtime.h>
#include <hip/hip_bf16.h>
#include <math.h>

#define HW 128
#define NPIX (HW * HW)
#define NB 8
#define PH 130
#define PPIX (PH * PH)  // 16900

// fused tile: 2 rows x 32 cols; halo 4 x 34
#define HR3 4
#define HC3 34
#define NPXT3 (HR3 * HC3)   // 136
#define NCHUNK (NPXT3 * 8)  // 1088 16B-chunks

typedef __attribute__((ext_vector_type(8))) short bf16x8;
typedef __attribute__((ext_vector_type(4))) float f32x4;

static __device__ __forceinline__ short f2bf(float v) {
  union { float f; unsigned u; } a; a.f = v;
  unsigned r = a.u + 0x7fffu + ((a.u >> 16) & 1u);
  return (short)(r >> 16);
}
static __device__ __forceinline__ unsigned pkbf2(float lo, float hi) {
  __hip_bfloat162 pk = __float22bfloat162_rn(make_float2(lo, hi));
  union { __hip_bfloat162 h; unsigned u; } cv; cv.h = pk;
  return cv.u;
}
// async global->LDS 16B; LDS dest = wave-uniform base + lane*16
static __device__ __forceinline__ void gl_lds16(const void* g, void* l) {
  __builtin_amdgcn_global_load_lds(
      (const __attribute__((address_space(1))) unsigned int*)g,
      (__attribute__((address_space(3))) unsigned int*)l, 16, 0, 0);
}

// ------------------------------------------------------------------
// prepack (blocks 0..143): Apack[p][64 m][64 n], A1pack[p][16 q][64 n];
// border-zero xT (blocks 144..151, one per batch)
__global__ __launch_bounds__(256) void k_pack(const float* __restrict__ wgt,
                                              const float* __restrict__ a1w1,
                                              short* __restrict__ Apack,
                                              short* __restrict__ A1pack,
                                              short* __restrict__ xT) {
  int bx = blockIdx.x;
  if (bx < 144) {
    int idx = bx * 256 + threadIdx.x;
    if (idx < 9 * 64 * 64) {
      int p = idx >> 12, m = (idx >> 6) & 63, n = idx & 63;
      Apack[idx] = f2bf(wgt[(m * 64 + n) * 9 + p]);
    }
    if (idx < 9 * 16 * 64) {
      int p = idx >> 10, q = (idx >> 6) & 15, n = idx & 63;
      A1pack[idx] = (q < 9) ? f2bf(a1w1[(q * 64 + n) * 9 + p]) : (short)0;
    }
  } else {
    int b = bx - 144;
    for (int c = threadIdx.x; c < 4128; c += 256) {
      int i = c >> 3, q = c & 7;
      int gpix;
      if (i < 130) gpix = i;
      else if (i < 260) gpix = 129 * 130 + (i - 130);
      else { int j = i - 260; gpix = (1 + (j >> 1)) * PH + ((j & 1) ? 129 : 0); }
      *(uint4*)(xT + ((size_t)b * PPIX + gpix) * 64 + q * 8) = make_uint4(0, 0, 0, 0);
    }
  }
}

// ------------------------------------------------------------------
// transpose x -> xT[b][padded pix][64ch] bf16 (pure copy, no reduction)
__global__ __launch_bounds__(256) void k_tr(const float* __restrict__ x,
                                            short* __restrict__ xT) {
  int b = blockIdx.y;
  int tid = threadIdx.x;
  int pix = (blockIdx.x << 8) + tid;
  const float* xb = x + (size_t)b * 64 * NPIX + pix;
  unsigned pk[32];
  #pragma unroll
  for (int cp = 0; cp < 32; cp++) {
    float v0 = xb[(size_t)(2 * cp) * NPIX];
    float v1 = xb[(size_t)(2 * cp + 1) * NPIX];
    pk[cp] = pkbf2(v0, v1);
  }
  int row = pix >> 7, col = pix & 127;
  short* dst = xT + ((size_t)b * PPIX + (size_t)(row + 1) * PH + (col + 1)) * 64;
  #pragma unroll
  for (int q = 0; q < 8; q++)
    *(uint4*)(dst + q * 8) =
        make_uint4(pk[4 * q], pk[4 * q + 1], pk[4 * q + 2], pk[4 * q + 3]);
}

// ------------------------------------------------------------------
// global average pool: one block per (b, n), float4 loads (round-2 proven)
__global__ __launch_bounds__(256) void k_gpool(const float* __restrict__ x,
                                               float* __restrict__ g) {
  int bn = blockIdx.x;
  const float4* p = (const float4*)(x + (size_t)bn * NPIX);
  float s = 0.f;
  #pragma unroll 4
  for (int i = threadIdx.x; i < NPIX / 4; i += 256) {
    float4 v = p[i];
    s += v.x + v.y + v.z + v.w;
  }
  #pragma unroll
  for (int o = 32; o > 0; o >>= 1) s += __shfl_down(s, o, 64);
  __shared__ float red[4];
  int lane = threadIdx.x & 63, wid = threadIdx.x >> 6;
  if (lane == 0) red[wid] = s;
  __syncthreads();
  if (threadIdx.x == 0)
    g[bn] = (red[0] + red[1] + red[2] + red[3]) * (1.0f / NPIX);
}

// ------------------------------------------------------------------
// dynamic bias: one block (64 threads) per batch (proven)
__global__ __launch_bounds__(64) void k_bias(const float* __restrict__ g,
                                             const float* __restrict__ a3w1,
                                             const float* __restrict__ a3b1,
                                             const float* __restrict__ a3w2,
                                             const float* __restrict__ a3b2,
                                             float* __restrict__ bias) {
  int b = blockIdx.x;
  int t = threadIdx.x;
  __shared__ float h[64];
  float s = a3b1[t];
  #pragma unroll
  for (int n = 0; n < 64; n++) s += a3w1[t * 64 + n] * g[b * 64 + n];
  h[t] = fmaxf(s, 0.f);
  __syncthreads();
  float s2 = a3b2[t];
  #pragma unroll
  for (int c = 0; c < 64; c++) s2 += a3w2[t * 64 + c] * h[c];
  bias[b * 64 + t] = s2;
}

// ------------------------------------------------------------------
// fused v3: async-stage xT tile -> conv1 MFMA -> shfl-MLP -> main MFMA
// block 256 thr = 4 waves; tile 2 rows x 32 cols; wave = 1 row x 16 cols.
// LDS chunk c stores global chunk (pix=c>>3, q=(c&7)^(pix&7)); reads XOR back.
__global__ __launch_bounds__(256, 6) void k_fused(
    const short* __restrict__ xT, const short* __restrict__ Apack,
    const short* __restrict__ A1pack,
    const float* __restrict__ b1p, const float* __restrict__ w2p,
    const float* __restrict__ b2p, const float* __restrict__ w3p,
    const float* __restrict__ b3p,
    const float* __restrict__ bias, float* __restrict__ out) {
  __shared__ short xt[NPXT3 * 64];  // 17408 B

  // XCD-aware decode: 2048 blocks = 8 XCD chunks x 256
  int bx = blockIdx.x;
  int swz = (bx & 7) * 256 + (bx >> 3);
  int b = swz >> 8;
  int rem = swz & 255;
  int ty = rem >> 2, tx = rem & 3;
  int row0 = ty * 2, col0 = tx * 32;

  int tid = threadIdx.x;
  int wid = tid >> 6, lane = tid & 63;
  int lp = lane & 15, kq = lane >> 4;
  int wr = wid >> 1, cg = wid & 1;  // wave's row (0,1) and col-group (0,1)

  // ---- async stage: 1088 chunks, 4 full iters + 64-chunk tail (wave 0)
  {
    const short* xTb = xT + (size_t)b * PPIX * 64;
    int base = row0 * PH + col0;  // halo origin in padded coords
    #pragma unroll
    for (int it = 0; it < 4; it++) {
      int c = it * 256 + tid;
      int pix = c >> 3, q = c & 7;
      int r = pix / HC3, col = pix - r * HC3;
      int qs = q ^ (pix & 7);
      const short* src = xTb + ((size_t)(base + r * PH + col)) * 64 + qs * 8;
      void* ldst = (char*)xt + (it * 256 + wid * 64) * 16;
      gl_lds16(src, ldst);
    }
    if (tid < 64) {
      int c = 1024 + tid;
      int pix = c >> 3, q = c & 7;
      int r = pix / HC3, col = pix - r * HC3;
      int qs = q ^ (pix & 7);
      const short* src = xTb + ((size_t)(base + r * PH + col)) * 64 + qs * 8;
      void* ldst = (char*)xt + 1024 * 16;
      gl_lds16(src, ldst);
    }
  }
  __syncthreads();

  // ---- phase 1: conv1 via MFMA (M=16 padded with zero rows, K=576)
  f32x4 acc1 = (f32x4){0.f, 0.f, 0.f, 0.f};
  #pragma unroll
  for (int p = 0; p < 9; p++) {
    const int di = p / 3, dj = p % 3;
    int pixb = (wr + di) * HC3 + cg * 16 + dj;
    #pragma unroll
    for (int ck = 0; ck < 2; ck++) {
      bf16x8 af1 = *(const bf16x8*)(A1pack + (p * 16 + lp) * 64 + ck * 32 + kq * 8);
      int pix = pixb + lp;
      int byteoff = (pix * 128 + ck * 64 + kq * 16) ^ ((pix & 7) << 4);
      bf16x8 bf = *(const bf16x8*)((const char*)xt + byteoff);
      acc1 = __builtin_amdgcn_mfma_f32_16x16x32_bf16(af1, bf, acc1, 0, 0, 0);
    }
  }

  // ---- phase 2: MLP, every lane redundantly computes pixel (lane&15)
  // gather a[q] from lane (q>>2)*16 + lp, reg q&3
  float aw[9];
  {
    float a[9], t1[9], t2[9];
    #pragma unroll
    for (int q2 = 0; q2 < 9; q2++)
      a[q2] = __shfl(acc1[q2 & 3], (q2 >> 2) * 16 + lp, 64);
    #pragma unroll
    for (int q = 0; q < 9; q++) t1[q] = fmaxf(a[q] + b1p[q], 0.f);
    #pragma unroll
    for (int r = 0; r < 9; r++) {
      float s = b2p[r];
      #pragma unroll
      for (int q = 0; q < 9; q++) s += w2p[r * 9 + q] * t1[q];
      t2[r] = fmaxf(s, 0.f);
    }
    #pragma unroll
    for (int r = 0; r < 9; r++) {
      float s = b3p[r];
      #pragma unroll
      for (int q = 0; q < 9; q++) s += w3p[r * 9 + q] * t2[q];
      aw[r] = 1.f / (1.f + __expf(-s));
    }
  }

  // ---- phase 3: main conv; raw-x MFMA per tap, then scale-accumulate by aw
  f32x4 acc[4];
  #pragma unroll
  for (int mt = 0; mt < 4; mt++) acc[mt] = (f32x4){0.f, 0.f, 0.f, 0.f};

  #pragma unroll
  for (int p = 0; p < 9; p++) {
    const int di = p / 3, dj = p % 3;
    int pix = (wr + di) * HC3 + cg * 16 + dj + lp;
    bf16x8 frag[2];
    #pragma unroll
    for (int ck = 0; ck < 2; ck++) {
      int byteoff = (pix * 128 + ck * 64 + kq * 16) ^ ((pix & 7) << 4);
      frag[ck] = *(const bf16x8*)((const char*)xt + byteoff);
    }
    float awp = aw[p];
    #pragma unroll
    for (int mt = 0; mt < 4; mt++) {
      const short* ap = Apack + (p * 64 + mt * 16 + lp) * 64 + kq * 8;
      bf16x8 af0 = *(const bf16x8*)(ap);
      bf16x8 af1 = *(const bf16x8*)(ap + 32);
      f32x4 tmp = (f32x4){0.f, 0.f, 0.f, 0.f};
      tmp = __builtin_amdgcn_mfma_f32_16x16x32_bf16(af0, frag[0], tmp, 0, 0, 0);
      tmp = __builtin_amdgcn_mfma_f32_16x16x32_bf16(af1, frag[1], tmp, 0, 0, 0);
      #pragma unroll
      for (int r = 0; r < 4; r++) acc[mt][r] += awp * tmp[r];
    }
  }

  // ---- epilogue: bias + store
  int i = row0 + wr;
  int j = col0 + cg * 16 + lp;
  #pragma unroll
  for (int mt = 0; mt < 4; mt++) {
    f32x4 bv = *(const f32x4*)(bias + b * 64 + mt * 16 + kq * 4);
    #pragma unroll
    for (int r = 0; r < 4; r++) {
      int m = mt * 16 + kq * 4 + r;
      out[(((size_t)b * 64 + m) * HW + i) * HW + j] = acc[mt][r] + bv[r];
    }
  }
}

// ------------------------------------------------------------------
extern "C" void kernel_launch(void* const* d_in, const int* in_sizes, int n_in,
                              void* d_out, int out_size, void* d_ws, size_t ws_size,
                              hipStream_t stream) {
  const float* x    = (const float*)d_in[0];
  const float* a1w1 = (const float*)d_in[1];
  const float* a1b1 = (const float*)d_in[2];
  const float* a1w2 = (const float*)d_in[3];
  const float* a1b2 = (const float*)d_in[4];
  const float* a1w3 = (const float*)d_in[5];
  const float* a1b3 = (const float*)d_in[6];
  const float* a3w1 = (const float*)d_in[7];
  const float* a3b1 = (const float*)d_in[8];
  const float* a3w2 = (const float*)d_in[9];
  const float* a3b2 = (const float*)d_in[10];
  const float* wgt  = (const float*)d_in[11];
  float* out = (float*)d_out;

  const size_t xT_sh = (size_t)NB * PPIX * 64;  // shorts
  short* xT     = (short*)d_ws;
  float* g      = (float*)(xT + xT_sh);         // 512
  float* bias   = g + NB * 64;                  // 512
  short* Apack  = (short*)(bias + NB * 64);     // 9*64*64
  short* A1pack = Apack + 9 * 64 * 64;          // 9*16*64

  k_pack<<<dim3(152), dim3(256), 0, stream>>>(wgt, a1w1, Apack, A1pack, xT);
  k_tr<<<dim3(64, NB), dim3(256), 0, stream>>>(x, xT);
  k_gpool<<<dim3(NB * 64), dim3(256), 0, stream>>>(x, g);
  k_bias<<<dim3(NB), dim3(64), 0, stream>>>(g, a3w1, a3b1, a3w2, a3b2, bias);
  k_fused<<<dim3(2048), dim3(256), 0, stream>>>(xT, Apack, A1pack,
                                                a1b1, a1w2, a1b2, a1w3, a1b3,
                                                bias, out);
}

// Round 6
// 135.211 us; speedup vs baseline: 1.0457x; 1.0457x over previous
//
#include <hip/hip_runtime.h>
#include <hip/hip_bf16.h>
#include <math.h>

#define HW 128
#define NPIX (HW * HW)
#define NB 8
#define PH 130
#define PPIX (PH * PH)  // 16900

// fused tile: 4 rows x 32 cols; halo 6 x 34
#define HR3 6
#define HC3 34
#define NPXT3 (HR3 * HC3)   // 204
#define NCHUNK (NPXT3 * 8)  // 1632 16B-chunks

typedef __attribute__((ext_vector_type(8))) short bf16x8;
typedef __attribute__((ext_vector_type(4))) float f32x4;

static __device__ __forceinline__ short f2bf(float v) {
  union { float f; unsigned u; } a; a.f = v;
  unsigned r = a.u + 0x7fffu + ((a.u >> 16) & 1u);
  return (short)(r >> 16);
}
static __device__ __forceinline__ unsigned pkbf2(float lo, float hi) {
  __hip_bfloat162 pk = __float22bfloat162_rn(make_float2(lo, hi));
  union { __hip_bfloat162 h; unsigned u; } cv; cv.h = pk;
  return cv.u;
}
static __device__ __forceinline__ float bfu(unsigned u) {
  union { unsigned u; float f; } a; a.u = u; return a.f;
}
// async global->LDS 16B; LDS dest = wave-uniform base + lane*16
static __device__ __forceinline__ void gl_lds16(const void* g, void* l) {
  __builtin_amdgcn_global_load_lds(
      (const __attribute__((address_space(1))) unsigned int*)g,
      (__attribute__((address_space(3))) unsigned int*)l, 16, 0, 0);
}

// ------------------------------------------------------------------
// prepack (blocks 0..143): Apack[p][64 m][64 n], A1pack[p][16 q][64 n];
// border-zero xT (blocks 144..151, one per batch)
__global__ __launch_bounds__(256) void k_pack(const float* __restrict__ wgt,
                                              const float* __restrict__ a1w1,
                                              short* __restrict__ Apack,
                                              short* __restrict__ A1pack,
                                              short* __restrict__ xT) {
  int bx = blockIdx.x;
  if (bx < 144) {
    int idx = bx * 256 + threadIdx.x;
    if (idx < 9 * 64 * 64) {
      int p = idx >> 12, m = (idx >> 6) & 63, n = idx & 63;
      Apack[idx] = f2bf(wgt[(m * 64 + n) * 9 + p]);
    }
    if (idx < 9 * 16 * 64) {
      int p = idx >> 10, q = (idx >> 6) & 15, n = idx & 63;
      A1pack[idx] = (q < 9) ? f2bf(a1w1[(q * 64 + n) * 9 + p]) : (short)0;
    }
  } else {
    int b = bx - 144;
    for (int c = threadIdx.x; c < 4128; c += 256) {
      int i = c >> 3, q = c & 7;
      int gpix;
      if (i < 130) gpix = i;
      else if (i < 260) gpix = 129 * 130 + (i - 130);
      else { int j = i - 260; gpix = (1 + (j >> 1)) * PH + ((j & 1) ? 129 : 0); }
      *(uint4*)(xT + ((size_t)b * PPIX + gpix) * 64 + q * 8) = make_uint4(0, 0, 0, 0);
    }
  }
}

// ------------------------------------------------------------------
// transpose x -> xT[b][padded pix][64ch] bf16
__global__ __launch_bounds__(256) void k_tr(const float* __restrict__ x,
                                            short* __restrict__ xT) {
  int b = blockIdx.y;
  int tid = threadIdx.x;
  int pix = (blockIdx.x << 8) + tid;
  const float* xb = x + (size_t)b * 64 * NPIX + pix;
  unsigned pk[32];
  #pragma unroll
  for (int cp = 0; cp < 32; cp++) {
    float v0 = xb[(size_t)(2 * cp) * NPIX];
    float v1 = xb[(size_t)(2 * cp + 1) * NPIX];
    pk[cp] = pkbf2(v0, v1);
  }
  int row = pix >> 7, col = pix & 127;
  short* dst = xT + ((size_t)b * PPIX + (size_t)(row + 1) * PH + (col + 1)) * 64;
  #pragma unroll
  for (int q = 0; q < 8; q++)
    *(uint4*)(dst + q * 8) =
        make_uint4(pk[4 * q], pk[4 * q + 1], pk[4 * q + 2], pk[4 * q + 3]);
}

// ------------------------------------------------------------------
// gpool from xT (bf16, half the traffic), deterministic two-stage reduce
// grid (8 strips, NB); block 256: thread = (slot 0..31, chunk q 0..7)
__global__ __launch_bounds__(256) void k_gpool2(const short* __restrict__ xT,
                                                float* __restrict__ part) {
  int b = blockIdx.y, strip = blockIdx.x;
  int tid = threadIdx.x;
  int wid = tid >> 6, lane = tid & 63;
  int q = tid & 7, slot = tid >> 3;
  const short* xb = xT + (size_t)b * PPIX * 64;
  float s[8];
  #pragma unroll
  for (int k = 0; k < 8; k++) s[k] = 0.f;
  #pragma unroll 4
  for (int itr = 0; itr < 64; itr++) {
    int px = strip * 2048 + itr * 32 + slot;
    int r = px >> 7, c = px & 127;
    uint4 v = *(const uint4*)(xb + ((size_t)((r + 1) * PH + c + 1)) * 64 + q * 8);
    s[0] += bfu(v.x << 16); s[1] += bfu(v.x & 0xffff0000u);
    s[2] += bfu(v.y << 16); s[3] += bfu(v.y & 0xffff0000u);
    s[4] += bfu(v.z << 16); s[5] += bfu(v.z & 0xffff0000u);
    s[6] += bfu(v.w << 16); s[7] += bfu(v.w & 0xffff0000u);
  }
  // reduce the 8 lanes sharing q within each wave
  #pragma unroll
  for (int o = 8; o < 64; o <<= 1)
    #pragma unroll
    for (int k = 0; k < 8; k++) s[k] += __shfl_down(s[k], o, 64);
  __shared__ float red[4][64];
  if (lane < 8) {
    #pragma unroll
    for (int k = 0; k < 8; k++) red[wid][lane * 8 + k] = s[k];
  }
  __syncthreads();
  if (tid < 64)
    part[((size_t)b * 8 + strip) * 64 + tid] =
        red[0][tid] + red[1][tid] + red[2][tid] + red[3][tid];
}

// ------------------------------------------------------------------
// dynamic bias from partials: one block (64 threads) per batch
__global__ __launch_bounds__(64) void k_bias(const float* __restrict__ part,
                                             const float* __restrict__ a3w1,
                                             const float* __restrict__ a3b1,
                                             const float* __restrict__ a3w2,
                                             const float* __restrict__ a3b2,
                                             float* __restrict__ bias) {
  int b = blockIdx.x;
  int t = threadIdx.x;
  __shared__ float gsh[64], h[64];
  float gs = 0.f;
  #pragma unroll
  for (int sIdx = 0; sIdx < 8; sIdx++) gs += part[((size_t)b * 8 + sIdx) * 64 + t];
  gsh[t] = gs * (1.0f / NPIX);
  __syncthreads();
  float s1 = a3b1[t];
  #pragma unroll
  for (int n = 0; n < 64; n++) s1 += a3w1[t * 64 + n] * gsh[n];
  h[t] = fmaxf(s1, 0.f);
  __syncthreads();
  float s2 = a3b2[t];
  #pragma unroll
  for (int c = 0; c < 64; c++) s2 += a3w2[t * 64 + c] * h[c];
  bias[b * 64 + t] = s2;
}

// ------------------------------------------------------------------
// fused v4: tile 4x32, 4 waves, wave = 1 row x 32 px (full-line stores);
// 1-deep A-fragment software pipeline; MLP overlaps main-A[0] latency.
__global__ __launch_bounds__(256, 3) void k_fused(
    const short* __restrict__ xT, const short* __restrict__ Apack,
    const short* __restrict__ A1pack,
    const float* __restrict__ b1p, const float* __restrict__ w2p,
    const float* __restrict__ b2p, const float* __restrict__ w3p,
    const float* __restrict__ b3p,
    const float* __restrict__ bias, float* __restrict__ out) {
  __shared__ short xt[NPXT3 * 64];  // 26112 B

  // XCD swizzle: 1024 blocks = 8 XCDs x 128; each XCD serves one batch
  int bx = blockIdx.x;
  int swz = (bx & 7) * 128 + (bx >> 3);
  int b = swz >> 7;
  int rem = swz & 127;
  int ty = rem >> 2, tx = rem & 3;
  int row0 = ty * 4, col0 = tx * 32;

  int tid = threadIdx.x;
  int wid = tid >> 6, lane = tid & 63;
  int lp = lane & 15, kq = lane >> 4;
  int wr = wid;  // wave's pixel row within tile

  // ---- async stage: 1632 chunks; LDS chunk c holds global q = (c&7)^(pix&7)
  {
    const short* xTb = xT + (size_t)b * PPIX * 64;
    int base = row0 * PH + col0;
    #pragma unroll
    for (int it = 0; it < 7; it++) {
      int c = it * 256 + tid;
      if (c < NCHUNK) {
        int pix = c >> 3, q = c & 7;
        int r = pix / HC3, col = pix - r * HC3;
        int qs = q ^ (pix & 7);
        const short* src = xTb + ((size_t)(base + r * PH + col)) * 64 + qs * 8;
        gl_lds16(src, (char*)xt + (it * 256 + wid * 64) * 16);
      }
    }
  }
  __syncthreads();

  // ---- phase 1: conv1 MFMA, 1-deep A1 prefetch
  bf16x8 a1b_[2][2];
  #pragma unroll
  for (int ck = 0; ck < 2; ck++)
    a1b_[0][ck] = *(const bf16x8*)(A1pack + (0 * 16 + lp) * 64 + ck * 32 + kq * 8);
  f32x4 acc1[2];
  acc1[0] = acc1[1] = (f32x4){0.f, 0.f, 0.f, 0.f};
  #pragma unroll
  for (int p = 0; p < 9; p++) {
    if (p < 8) {
      #pragma unroll
      for (int ck = 0; ck < 2; ck++)
        a1b_[(p + 1) & 1][ck] =
            *(const bf16x8*)(A1pack + ((p + 1) * 16 + lp) * 64 + ck * 32 + kq * 8);
    }
    const int di = p / 3, dj = p % 3;
    #pragma unroll
    for (int g = 0; g < 2; g++) {
      int pix = (wr + di) * HC3 + g * 16 + dj + lp;
      #pragma unroll
      for (int ck = 0; ck < 2; ck++) {
        int byteoff = (pix * 128 + ck * 64 + kq * 16) ^ ((pix & 7) << 4);
        bf16x8 bf = *(const bf16x8*)((const char*)xt + byteoff);
        acc1[g] = __builtin_amdgcn_mfma_f32_16x16x32_bf16(a1b_[p & 1][ck], bf, acc1[g], 0, 0, 0);
      }
    }
  }

  // ---- prefetch main-conv tap-0 A fragments (latency hidden by MLP below)
  bf16x8 ab_[2][4][2];
  #pragma unroll
  for (int mt = 0; mt < 4; mt++)
    #pragma unroll
    for (int ck = 0; ck < 2; ck++)
      ab_[0][mt][ck] =
          *(const bf16x8*)(Apack + ((0 * 64 + mt * 16 + lp) * 64 + ck * 32 + kq * 8));

  // ---- phase 2: MLP, every lane computes pixel (lane&15) of each group
  float aw[2][9];
  #pragma unroll
  for (int g = 0; g < 2; g++) {
    float a[9], t1[9], t2[9];
    #pragma unroll
    for (int q2 = 0; q2 < 9; q2++)
      a[q2] = __shfl(acc1[g][q2 & 3], (q2 >> 2) * 16 + lp, 64);
    #pragma unroll
    for (int q = 0; q < 9; q++) t1[q] = fmaxf(a[q] + b1p[q], 0.f);
    #pragma unroll
    for (int r = 0; r < 9; r++) {
      float s = b2p[r];
      #pragma unroll
      for (int q = 0; q < 9; q++) s += w2p[r * 9 + q] * t1[q];
      t2[r] = fmaxf(s, 0.f);
    }
    #pragma unroll
    for (int r = 0; r < 9; r++) {
      float s = b3p[r];
      #pragma unroll
      for (int q = 0; q < 9; q++) s += w3p[r * 9 + q] * t2[q];
      aw[g][r] = 1.f / (1.f + __expf(-s));
    }
  }

  // ---- phase 3: main conv, 1-deep A prefetch, scale-after-MFMA
  f32x4 acc[2][4];
  #pragma unroll
  for (int g = 0; g < 2; g++)
    #pragma unroll
    for (int mt = 0; mt < 4; mt++) acc[g][mt] = (f32x4){0.f, 0.f, 0.f, 0.f};

  #pragma unroll
  for (int p = 0; p < 9; p++) {
    if (p < 8) {
      #pragma unroll
      for (int mt = 0; mt < 4; mt++)
        #pragma unroll
        for (int ck = 0; ck < 2; ck++)
          ab_[(p + 1) & 1][mt][ck] = *(const bf16x8*)(
              Apack + (((p + 1) * 64 + mt * 16 + lp) * 64 + ck * 32 + kq * 8));
    }
    const int di = p / 3, dj = p % 3;
    bf16x8 fr[2][2];
    #pragma unroll
    for (int g = 0; g < 2; g++) {
      int pix = (wr + di) * HC3 + g * 16 + dj + lp;
      #pragma unroll
      for (int ck = 0; ck < 2; ck++) {
        int byteoff = (pix * 128 + ck * 64 + kq * 16) ^ ((pix & 7) << 4);
        fr[g][ck] = *(const bf16x8*)((const char*)xt + byteoff);
      }
    }
    #pragma unroll
    for (int mt = 0; mt < 4; mt++) {
      #pragma unroll
      for (int g = 0; g < 2; g++) {
        f32x4 tmp = (f32x4){0.f, 0.f, 0.f, 0.f};
        tmp = __builtin_amdgcn_mfma_f32_16x16x32_bf16(ab_[p & 1][mt][0], fr[g][0], tmp, 0, 0, 0);
        tmp = __builtin_amdgcn_mfma_f32_16x16x32_bf16(ab_[p & 1][mt][1], fr[g][1], tmp, 0, 0, 0);
        float awp = aw[g][p];
        #pragma unroll
        for (int r = 0; r < 4; r++) acc[g][mt][r] += awp * tmp[r];
      }
    }
  }

  // ---- epilogue: bias + full-line stores (both 16-px halves per wave)
  int i = row0 + wr;
  #pragma unroll
  for (int mt = 0; mt < 4; mt++) {
    f32x4 bv = *(const f32x4*)(bias + b * 64 + mt * 16 + kq * 4);
    #pragma unroll
    for (int r = 0; r < 4; r++) {
      int m = mt * 16 + kq * 4 + r;
      float* o = out + (((size_t)b * 64 + m) * HW + i) * HW;
      o[col0 + lp] = acc[0][mt][r] + bv[r];
      o[col0 + 16 + lp] = acc[1][mt][r] + bv[r];
    }
  }
}

// ------------------------------------------------------------------
extern "C" void kernel_launch(void* const* d_in, const int* in_sizes, int n_in,
                              void* d_out, int out_size, void* d_ws, size_t ws_size,
                              hipStream_t stream) {
  const float* x    = (const float*)d_in[0];
  const float* a1w1 = (const float*)d_in[1];
  const float* a1b1 = (const float*)d_in[2];
  const float* a1w2 = (const float*)d_in[3];
  const float* a1b2 = (const float*)d_in[4];
  const float* a1w3 = (const float*)d_in[5];
  const float* a1b3 = (const float*)d_in[6];
  const float* a3w1 = (const float*)d_in[7];
  const float* a3b1 = (const float*)d_in[8];
  const float* a3w2 = (const float*)d_in[9];
  const float* a3b2 = (const float*)d_in[10];
  const float* wgt  = (const float*)d_in[11];
  float* out = (float*)d_out;

  const size_t xT_sh = (size_t)NB * PPIX * 64;   // shorts
  short* xT     = (short*)d_ws;
  float* part   = (float*)(xT + xT_sh);          // NB*8*64 floats
  float* bias   = part + NB * 8 * 64;            // 512
  short* Apack  = (short*)(bias + NB * 64);      // 9*64*64
  short* A1pack = Apack + 9 * 64 * 64;           // 9*16*64

  k_pack<<<dim3(152), dim3(256), 0, stream>>>(wgt, a1w1, Apack, A1pack, xT);
  k_tr<<<dim3(64, NB), dim3(256), 0, stream>>>(x, xT);
  k_gpool2<<<dim3(8, NB), dim3(256), 0, stream>>>(xT, part);
  k_bias<<<dim3(NB), dim3(64), 0, stream>>>(part, a3w1, a3b1, a3w2, a3b2, bias);
  k_fused<<<dim3(1024), dim3(256), 0, stream>>>(xT, Apack, A1pack,
                                                a1b1, a1w2, a1b2, a1w3, a1b3,
                                                bias, out);
}